// Round 9
// baseline (47.562 us; speedup 1.0000x reference)
//
#include <hip/hip_runtime.h>
#include <math.h>

// N=4, M=64, A=64, O=5, F=256
// DIAGNOSTIC ROUND: identical to round-8 kernel, but k_out is launched TWICE
// (idempotent). dur_us(R9) - dur_us(R8) = duration of one k_out dispatch.
//
// Reduced algebra (post-filt structure):
//   G[n][u][b][a]: u<2 -> M[u][0]+M[u][1]; u=2 -> M[2][2]   (M = 5x bilinear+swish of S)
//   coup[b][k] = Y_k(unit(R)) * ||C[b,:]||
//   D0[b][i] = sum_k coup[b][k]*cgc[k][i][0]
//   Dz[b][i] = sum_k coup[b][k]*(cgc[k][i][1]+cgc[k][i][2]+cgc[k][i][3])
//   W3[nm][a][u][i] = sum_b G[n][u][b][a] * (u==2 ? Dz : D0)[b][i]
//   out[nm][f][i] = sum_a  W3[a][0][i]*(C[a,0]*ao[a,0,f])
//                        + W3[a][1][i]*(C[a,1]*ao[a,1,f])
//                        + W3[a][2][i]*(C[a,2]*ao[a,2,f]+C[a,3]*ao[a,3,f]+C[a,4]*ao[a,4,f])
//
// ws layout (floats): G off 0 (49152 f), W3 off 49152 (256*1792 = 458752 f)

typedef float v4f __attribute__((ext_vector_type(4)));
static __device__ inline v4f splat4(float s) { return (v4f){s, s, s, s}; }

__global__ void k_sc(const float* __restrict__ S, const float* __restrict__ wst,
                     float* __restrict__ G) {
    int t = blockIdx.x * 128 + threadIdx.x;   // 16384 threads over 128 blocks
    int n = t >> 12;
    int a = (t >> 6) & 63;   // row atom
    int b = t & 63;          // col atom
    float M[3][3];
#pragma unroll
    for (int x = 0; x < 3; ++x)
#pragma unroll
        for (int y = 0; y < 3; ++y)
            M[x][y] = S[(((n * 64 + a) * 3 + x) * 64 + b) * 3 + y];
#pragma unroll
    for (int it = 0; it < 5; ++it) {
        float w[3][3];
#pragma unroll
        for (int x = 0; x < 3; ++x)
#pragma unroll
            for (int y = 0; y < 3; ++y)
                w[x][y] = wst[it * 9 + x * 3 + y];
        float T[3][3];
#pragma unroll
        for (int x = 0; x < 3; ++x)
#pragma unroll
            for (int d = 0; d < 3; ++d)
                T[x][d] = w[x][0] * M[0][d] + w[x][1] * M[1][d] + w[x][2] * M[2][d];
#pragma unroll
        for (int x = 0; x < 3; ++x)
#pragma unroll
            for (int c = 0; c < 3; ++c) {
                float v = T[x][0] * w[c][0] + T[x][1] * w[c][1] + T[x][2] * w[c][2];
                M[x][c] = v / (1.f + expf(-v));   // swish
            }
    }
    float g0 = M[0][0] + M[0][1];
    float g1 = M[1][0] + M[1][1];
    float gz = M[2][2];
    size_t base = (size_t)n * 12288 + (size_t)b * 64 + a;
    G[base]          = g0;
    G[base + 4096]   = g1;
    G[base + 8192]   = gz;
}

// 576 threads = 9 waves: one W3 task per wave.
__global__ __launch_bounds__(576) void k_w3(
        const float* __restrict__ C, const float* __restrict__ R,
        const float* __restrict__ cgc, const float* __restrict__ G,
        float* __restrict__ wsW3) {
    __shared__ float s_coup[64 * 9];
    __shared__ float s_D[2 * 9 * 64];   // [pm][i][b]
    __shared__ float s_W3[64 * 27];     // [a][u][i]

    const int nm = blockIdx.x;
    const int n = nm >> 6;
    const int tid = threadIdx.x;

    if (tid < 64) {
        const int b = tid;
        const float* rp = R + ((size_t)nm * 64 + b) * 3;
        float x = rp[0], y = rp[1], z = rp[2];
        float rn = sqrtf(x * x + y * y + z * z) + 1e-12f;
        x /= rn; y /= rn; z /= rn;
        const float* cp = C + ((size_t)nm * 64 + b) * 5;
        float cn = 0.f;
#pragma unroll
        for (int o = 0; o < 5; ++o) cn += cp[o] * cp[o];
        cn = sqrtf(cn);
        const float c1 = 0.4886025119029199f;
        const float c2 = 1.0925484305920792f;
        float Y[9];
        Y[0] = 0.28209479177387814f;
        Y[1] = c1 * y;
        Y[2] = c1 * z;
        Y[3] = c1 * x;
        Y[4] = c2 * x * y;
        Y[5] = c2 * y * z;
        Y[6] = 0.31539156525252005f * (3.f * z * z - 1.f);
        Y[7] = c2 * x * z;
        Y[8] = 0.5462742152960396f * (x * x - y * y);
#pragma unroll
        for (int k = 0; k < 9; ++k) s_coup[b * 9 + k] = Y[k] * cn;
    }
    __syncthreads();

    // D[pm][i][b]: exactly 576 (b,i) pairs, one per thread
    {
        const int b = tid & 63, i = tid >> 6;
        float d0 = 0.f, dz = 0.f;
#pragma unroll
        for (int k = 0; k < 9; ++k) {
            float cp = s_coup[b * 9 + k];
            const float* cg = cgc + k * 81 + i * 9;
            d0 = fmaf(cp, cg[0], d0);
            dz = fmaf(cp, cg[1] + cg[2] + cg[3], dz);
        }
        s_D[(0 * 9 + i) * 64 + b] = d0;
        s_D[(1 * 9 + i) * 64 + b] = dz;
    }
    __syncthreads();

    // W3[a][u][i]: wave pp = (u, i-triple); lane = a
    const int pp = __builtin_amdgcn_readfirstlane(tid >> 6);  // 0..8
    const int lane = tid & 63;   // a
    {
        const int u = pp / 3;
        const int i0 = (pp % 3) * 3;
        const int pm = (u == 2) ? 1 : 0;
        const float* gp = G + (size_t)n * 12288 + (size_t)u * 4096 + lane;  // + b*64
        const float* dp = &s_D[(pm * 9 + i0) * 64];                          // + b
        float a0 = 0.f, a1 = 0.f, a2 = 0.f;
#pragma unroll 8
        for (int b = 0; b < 64; ++b) {
            float g = gp[b * 64];          // coalesced over lane=a
            a0 = fmaf(g, dp[b], a0);       // broadcast LDS reads (uniform addr)
            a1 = fmaf(g, dp[64 + b], a1);
            a2 = fmaf(g, dp[128 + b], a2);
        }
        s_W3[lane * 27 + u * 9 + i0 + 0] = a0;
        s_W3[lane * 27 + u * 9 + i0 + 1] = a1;
        s_W3[lane * 27 + u * 9 + i0 + 2] = a2;
    }
    __syncthreads();

    // export padded [a][28]
    float* wp = wsW3 + (size_t)nm * 1792;
    for (int e = tid; e < 1792; e += 576) {
        int a = e / 28, q = e - a * 28;
        wp[e] = (q < 27) ? s_W3[a * 27 + q] : 0.f;
    }
}

// Block = nm (256 blocks, 512 threads). Wave w owns f-window [w*32, w*32+32);
// lane: fgrp = lane&7 -> f0 = w*32+fgrp*4 (float4), agrp = lane>>3 -> a = agrp+8t.
__global__ __launch_bounds__(512) void k_out(
        const float* __restrict__ ao, const float* __restrict__ C,
        const float* __restrict__ wsW3, float* __restrict__ out) {
    __shared__ float s_W3[64 * 28];   // padded rows, 7 KB
    __shared__ float s_C[320];
    const int nm = blockIdx.x;
    const int tid = threadIdx.x;
    {
        const float* wp = wsW3 + (size_t)nm * 1792;
        for (int e = tid; e < 1792; e += 512) s_W3[e] = wp[e];
        const float* cp = C + (size_t)nm * 320;
        for (int e = tid; e < 320; e += 512) s_C[e] = cp[e];
    }
    __syncthreads();

    const int w = tid >> 6;
    const int lane = tid & 63;
    const int fgrp = lane & 7;
    const int agrp = lane >> 3;
    const int f0 = w * 32 + fgrp * 4;
    const float* ap = ao + (size_t)nm * 81920 + (size_t)agrp * 1280 + f0;

    v4f acc[9];
#pragma unroll
    for (int i = 0; i < 9; ++i) acc[i] = splat4(0.f);

#pragma unroll
    for (int t = 0; t < 8; ++t) {
        const int a = agrp + 8 * t;
        const float* aop = ap + t * 10240;
        v4f v0 = *(const v4f*)(aop + 0 * 256);
        v4f v1 = *(const v4f*)(aop + 1 * 256);
        v4f v2 = *(const v4f*)(aop + 2 * 256);
        v4f v3 = *(const v4f*)(aop + 3 * 256);
        v4f v4 = *(const v4f*)(aop + 4 * 256);
        const float* cc = &s_C[a * 5];
        v4f e0 = splat4(cc[0]) * v0;
        v4f e1 = splat4(cc[1]) * v1;
        v4f e2 = splat4(cc[2]) * v2 + splat4(cc[3]) * v3 + splat4(cc[4]) * v4;
        const float* w3 = &s_W3[a * 28];
#pragma unroll
        for (int i = 0; i < 9; ++i)
            acc[i] += splat4(w3[i]) * e0 + splat4(w3[9 + i]) * e1 + splat4(w3[18 + i]) * e2;
    }

    // reduce over the 8 agrp groups (lanes xor 8,16,32)
#pragma unroll
    for (int mask = 8; mask <= 32; mask <<= 1) {
#pragma unroll
        for (int i = 0; i < 9; ++i) {
#pragma unroll
            for (int j = 0; j < 4; ++j)
                acc[i][j] += __shfl_xor(acc[i][j], mask, 64);
        }
    }

    if (agrp == 0) {
        v4f buf4[9];
        float* bp = (float*)buf4;
#pragma unroll
        for (int j = 0; j < 4; ++j)
#pragma unroll
            for (int i = 0; i < 9; ++i)
                bp[j * 9 + i] = acc[i][j];
        float* op = out + (size_t)nm * 2304 + (size_t)f0 * 9;   // 16B-aligned
#pragma unroll
        for (int q = 0; q < 9; ++q)
            *(v4f*)(op + q * 4) = buf4[q];
    }
}

extern "C" void kernel_launch(void* const* d_in, const int* in_sizes, int n_in,
                              void* d_out, int out_size, void* d_ws, size_t ws_size,
                              hipStream_t stream) {
    (void)in_sizes; (void)n_in; (void)out_size; (void)ws_size;
    const float* ao  = (const float*)d_in[0];
    const float* C   = (const float*)d_in[1];
    const float* S   = (const float*)d_in[2];
    const float* R   = (const float*)d_in[3];
    const float* wst = (const float*)d_in[4];
    const float* cgc = (const float*)d_in[5];
    float* out = (float*)d_out;
    float* ws = (float*)d_ws;
    float* G    = ws;             // 49152 floats
    float* wsW3 = ws + 49152;     // 458752 floats

    hipLaunchKernelGGL(k_sc,  dim3(128), dim3(128), 0, stream, S, wst, G);
    hipLaunchKernelGGL(k_w3,  dim3(256), dim3(576), 0, stream, C, R, cgc, G, wsW3);
    // DIAGNOSTIC: k_out launched twice (idempotent). Delta vs round 8 = dur(k_out).
    hipLaunchKernelGGL(k_out, dim3(256), dim3(512), 0, stream, ao, C, wsW3, out);
    hipLaunchKernelGGL(k_out, dim3(256), dim3(512), 0, stream, ao, C, wsW3, out);
}